// Round 5
// baseline (296.797 us; speedup 1.0000x reference)
//
#include <hip/hip_runtime.h>
#include <hip/hip_bf16.h>

// out = x @ (qw*scale)^T + b  => GEMM M=8192, N=8192, K=2048, bf16 MFMA.
// R5: switch MFMA shape 16x16x32 -> 32x32x16 (m119: 2495 vs 2176 TF ceiling,
// fewer issue slots), keep R4's verified 8-phase schedule/staging/vmcnt
// unchanged. Swizzle uniformity re-verified for the 32x32 read pattern.
// Converts merged into one launch. Epilogue now 2x128B segments per store.

#define M_DIM 8192
#define N_DIM 8192
#define K_DIM 2048
#define NT    (K_DIM / 64)   // 32 K-tiles (BK=64), 2 per iteration

typedef __attribute__((ext_vector_type(8)))  short bf16x8;
typedef __attribute__((ext_vector_type(16))) float f32x16;

__device__ __forceinline__ ushort f2bf(float f) {
    union { float f; unsigned int u; } v; v.f = f;
    unsigned int u = v.u;
    return (ushort)((u + 0x7fffu + ((u >> 16) & 1u)) >> 16);  // RNE
}

// Fused convert: chunks [0, n4) = x (fp32->bf16), [n4, 2*n4) = w (int->bf16).
__global__ void cvt_kernel(const float* __restrict__ x, const int* __restrict__ w,
                           ushort* __restrict__ xb, ushort* __restrict__ wb, int n4) {
    int i = blockIdx.x * blockDim.x + threadIdx.x;
    if (i < n4) {
        const float4 v = reinterpret_cast<const float4*>(x)[i];
        ushort4 r;
        r.x = f2bf(v.x); r.y = f2bf(v.y); r.z = f2bf(v.z); r.w = f2bf(v.w);
        reinterpret_cast<ushort4*>(xb)[i] = r;
    } else {
        int j = i - n4;
        const int4 v = reinterpret_cast<const int4*>(w)[j];
        ushort4 r;
        r.x = f2bf((float)v.x); r.y = f2bf((float)v.y);
        r.z = f2bf((float)v.z); r.w = f2bf((float)v.w);
        reinterpret_cast<ushort4*>(wb)[j] = r;
    }
}

// Piece = [256 rows][32 k] bf16 = 16 KiB, 2 gload_lds/thread. lds[buf][op][kh].
// Stage map (iteration i, tiles t=2i buf0 / t+1 buf1):
//  p0: (1,A,kh1)<-t+1   p1: (1,B,kh1)<-t+1   p2: (0,A,kh0)<-t+2  p3: (0,B,kh0)<-t+2
//  p4: (0,A,kh1)<-t+2   p5: (0,B,kh1)<-t+2   p6: (1,A,kh0)<-t+3  p7: (1,B,kh0)<-t+3
// Reads: p0/p1 buf0 kh0 (mh0/mh1), p2/p3 buf0 kh1, p4/p5 buf1 kh0, p6/p7 buf1 kh1.
// vmcnt(8) at odd phases drains the 2 pieces the next even phase reads
// (12 in flight steady). Tail: 8/4/0/skip. WAR/RAW verified in R3/R4.
// MFMA: 32x32x16 bf16. Per wave output 128x64 = 4 m-frags x 2 n-frags (32x32).
// A-frag: row = lane&31, k = (lane>>5)*8 + j. C/D: col = lane&31,
// row = (reg&3) + 8*(reg>>2) + 4*(lane>>5)  [m74/m101 verified].
__global__ __launch_bounds__(512, 2) void gemm_bf16_kernel(
    const ushort* __restrict__ A,   // [M][K] bf16
    const ushort* __restrict__ B,   // [N][K] bf16
    const float* __restrict__ scale_p,
    const float* __restrict__ bias,
    float* __restrict__ C)          // [M][N] fp32
{
    __shared__ __align__(16) ushort lds[2][2][2][8192];

    const int tid  = threadIdx.x;
    const int lane = tid & 63;
    const int wave = tid >> 6;
    const int wr = wave >> 2;        // 0..1 (128-row M half)
    const int wc = wave & 3;         // 0..3 (64-col N quarter)
    const int bm = blockIdx.y;
    const int bn = blockIdx.x;

    const ushort* gA = A + (size_t)(bm * 256) * K_DIM;
    const ushort* gB = B + (size_t)(bn * 256) * K_DIM;

    const int sr = tid >> 2;                       // 0..127
    const int sg = (tid & 3) ^ ((tid >> 3) & 3);   // pre-swizzled source granule
    const ushort* sA0 = gA + (size_t)sr * K_DIM + sg * 8;
    const ushort* sA1 = gA + (size_t)(sr + 128) * K_DIM + sg * 8;
    const ushort* sB0 = gB + (size_t)sr * K_DIM + sg * 8;
    const ushort* sB1 = gB + (size_t)(sr + 128) * K_DIM + sg * 8;

#define GLDS(src, dst) __builtin_amdgcn_global_load_lds( \
    (const __attribute__((address_space(1))) unsigned int*)(src), \
    (__attribute__((address_space(3))) unsigned int*)(dst), 16, 0, 0)

#define STAGE_P(buf, op, kh, kt) do { \
    const int _c = (kt) * 64 + (kh) * 32; \
    GLDS(((op) ? sB0 : sA0) + _c, &lds[buf][op][kh][tid * 8]); \
    GLDS(((op) ? sB1 : sA1) + _c, &lds[buf][op][kh][tid * 8 + 4096]); \
} while (0)

    f32x16 acc[4][2];   // [m-frag global][n-frag], 128 accum regs
#pragma unroll
    for (int m = 0; m < 4; ++m)
#pragma unroll
        for (int n = 0; n < 2; ++n)
#pragma unroll
            for (int q = 0; q < 16; ++q)
                acc[m][n][q] = 0.f;

    const int l31 = lane & 31;
    const int kx  = lane >> 5;       // k-half select
    // swizzled granule byte offset for ks=0/1:
    //   g = ks*2 + kx; g' = g ^ ((row>>1)&3); row base multiple of 32 -> (l31>>1)&3
    const int swp = (l31 >> 1) & 3;
    const int sw0 = ((0 + kx) ^ swp) << 4;
    const int sw1 = ((2 + kx) ^ swp) << 4;
    const int rowA = (wr * 128 + l31) * 64;   // + mh*4096 + m*2048
    const int rowB = (wc * 64  + l31) * 64;   // + n*2048

    bf16x8 af[4], bfr[4];   // [frag*2 + ks]

#define DS_AF(buf, kh, mh) do { \
    const char* _p = (const char*)&lds[buf][0][kh][0] + rowA + (mh) * 4096; \
    af[0] = *(const bf16x8*)(_p + sw0);        af[1] = *(const bf16x8*)(_p + sw1); \
    af[2] = *(const bf16x8*)(_p + 2048 + sw0); af[3] = *(const bf16x8*)(_p + 2048 + sw1); \
} while (0)

#define DS_BF(buf, kh) do { \
    const char* _p = (const char*)&lds[buf][1][kh][0] + rowB; \
    bfr[0] = *(const bf16x8*)(_p + sw0);        bfr[1] = *(const bf16x8*)(_p + sw1); \
    bfr[2] = *(const bf16x8*)(_p + 2048 + sw0); bfr[3] = *(const bf16x8*)(_p + 2048 + sw1); \
} while (0)

// 8 MFMA: ks outer (4 independent, then 4 dependent-on-4-back).
#define MFMA8(mh) do { \
    _Pragma("unroll") \
    for (int _ks = 0; _ks < 2; ++_ks) \
        _Pragma("unroll") \
        for (int _m = 0; _m < 2; ++_m) \
            _Pragma("unroll") \
            for (int _n = 0; _n < 2; ++_n) \
                acc[(mh) * 2 + _m][_n] = __builtin_amdgcn_mfma_f32_32x32x16_bf16( \
                    af[_m * 2 + _ks], bfr[_n * 2 + _ks], acc[(mh) * 2 + _m][_n], 0, 0, 0); \
} while (0)

#define BARRIER() do { __builtin_amdgcn_s_barrier(); asm volatile("" ::: "memory"); } while (0)

#define PH_EVEN(buf, kh, STG) do { \
    DS_AF(buf, kh, 0); DS_BF(buf, kh); \
    STG; \
    BARRIER(); \
    __builtin_amdgcn_s_setprio(1); MFMA8(0); __builtin_amdgcn_s_setprio(0); \
    BARRIER(); \
} while (0)

#define PH_ODD(buf, kh, STG, VM) do { \
    DS_AF(buf, kh, 1); \
    STG; \
    asm volatile("s_waitcnt vmcnt(" #VM ")" ::: "memory"); \
    BARRIER(); \
    __builtin_amdgcn_s_setprio(1); MFMA8(1); __builtin_amdgcn_s_setprio(0); \
    BARRIER(); \
} while (0)

    // Prologue: 6 pieces (12 loads): tile0 all + tile1 kh0; drain first 2 pieces.
    STAGE_P(0, 0, 0, 0); STAGE_P(0, 1, 0, 0);
    STAGE_P(0, 0, 1, 0); STAGE_P(0, 1, 1, 0);
    STAGE_P(1, 0, 0, 1); STAGE_P(1, 1, 0, 1);
    asm volatile("s_waitcnt vmcnt(8)" ::: "memory");
    BARRIER();

#pragma unroll 1
    for (int i = 0; i < NT / 2 - 1; ++i) {
        const int t = 2 * i;
        PH_EVEN(0, 0, STAGE_P(1, 0, 1, t + 1));
        PH_ODD (0, 0, STAGE_P(1, 1, 1, t + 1), 8);
        PH_EVEN(0, 1, STAGE_P(0, 0, 0, t + 2));
        PH_ODD (0, 1, STAGE_P(0, 1, 0, t + 2), 8);
        PH_EVEN(1, 0, STAGE_P(0, 0, 1, t + 2));
        PH_ODD (1, 0, STAGE_P(0, 1, 1, t + 2), 8);
        PH_EVEN(1, 1, STAGE_P(1, 0, 0, t + 3));
        PH_ODD (1, 1, STAGE_P(1, 1, 0, t + 3), 8);
    }
    {   // Peel: tail vmcnt 8/4/0/skip.
        PH_EVEN(0, 0, STAGE_P(1, 0, 1, NT - 1));
        PH_ODD (0, 0, STAGE_P(1, 1, 1, NT - 1), 8);
        PH_EVEN(0, 1, (void)0);
        PH_ODD (0, 1, (void)0, 4);
        PH_EVEN(1, 0, (void)0);
        PH_ODD (1, 0, (void)0, 0);
        PH_EVEN(1, 1, (void)0);
        {   // p7: nothing in flight, no trailing barrier needed
            DS_AF(1, 1, 1);
            __builtin_amdgcn_s_setprio(1); MFMA8(1); __builtin_amdgcn_s_setprio(0);
        }
    }

#undef PH_ODD
#undef PH_EVEN
#undef BARRIER
#undef MFMA8
#undef DS_BF
#undef DS_AF
#undef STAGE_P
#undef GLDS

    // Epilogue: 32x32 C/D layout: col = lane&31, row = (reg&3)+8*(reg>>2)+4*kx.
    const float s = scale_p[0];
#pragma unroll
    for (int mi = 0; mi < 4; ++mi) {
#pragma unroll
        for (int n = 0; n < 2; ++n) {
            const int col = bn * 256 + wc * 64 + n * 32 + l31;
            const float bb = bias[col];
            const int rbase = bm * 256 + wr * 128 + mi * 32 + 4 * kx;
#pragma unroll
            for (int q = 0; q < 16; ++q) {
                const int r = rbase + (q & 3) + 8 * (q >> 2);
                C[(size_t)r * N_DIM + col] = acc[mi][n][q] * s + bb;
            }
        }
    }
}

// Correctness-insurance fallback if ws_size < 64 MiB (should not trigger).
__global__ void naive_fallback(const float* __restrict__ x, const int* __restrict__ w,
                               const float* __restrict__ scale, const float* __restrict__ bias,
                               float* __restrict__ out) {
    size_t i = (size_t)blockIdx.x * blockDim.x + threadIdx.x;
    int m = (int)(i / N_DIM);
    int n = (int)(i % N_DIM);
    const float* xr = x + (size_t)m * K_DIM;
    const int*   wrw = w + (size_t)n * K_DIM;
    float acc = 0.f;
    for (int k = 0; k < K_DIM; ++k) acc += xr[k] * (float)wrw[k];
    out[i] = acc * scale[0] + bias[n];
}

extern "C" void kernel_launch(void* const* d_in, const int* in_sizes, int n_in,
                              void* d_out, int out_size, void* d_ws, size_t ws_size,
                              hipStream_t stream) {
    const float* x     = (const float*)d_in[0];
    const int*   qw    = (const int*)d_in[1];
    const float* scale = (const float*)d_in[2];
    const float* bias  = (const float*)d_in[3];
    float* out = (float*)d_out;

    const size_t elems = (size_t)M_DIM * K_DIM;          // 16,777,216
    const size_t need  = elems * 2u * sizeof(ushort);    // 64 MiB

    if (ws_size >= need) {
        ushort* xb = (ushort*)d_ws;
        ushort* wb = xb + elems;
        const int n4 = (int)(elems / 4);
        cvt_kernel<<<(2 * n4) / 256, 256, 0, stream>>>(x, qw, xb, wb, n4);
        dim3 grid(N_DIM / 256, M_DIM / 256);
        gemm_bf16_kernel<<<grid, 512, 0, stream>>>(xb, wb, scale, bias, out);
    } else {
        const size_t total = (size_t)M_DIM * N_DIM;
        naive_fallback<<<(int)(total / 256), 256, 0, stream>>>(x, qw, scale, bias, out);
    }
}